// Round 12
// baseline (310.217 us; speedup 1.0000x reference)
//
#include <hip/hip_runtime.h>
#include <math.h>

// Problem constants (from reference)
#define NQ 32768   // query points (pos1)
#define MC 8192    // source points (pos2)
#define CC 128     // channels
#define EPS_BN 1e-5f
#define EPS_D  1e-8

#define DBL_BIG 1e300
#define IDX_BIG 0x7fffffff

// KNN config (R11-proven: 77 us)
#define QB  64          // queries per block (1 per lane)
#define TB  512         // threads per block (8 waves)
#define NW  8           // waves per block
#define CH  2048        // candidates staged per chunk
#define HM  (MC / 2)    // half of M per block = 4096
#define NCH (HM / CH)   // 2 chunks per block
#define SLC (CH / NW)   // per-chunk per-wave slice = 256
#define KMASK 0xFFFFE000u   // keep sign+exp+10 mantissa bits
#define IMASK 0x1FFFu       // 13-bit index (M=8192)
#define NSURV 64            // survivors per query (2 halves x 8 waves x 4)
#define KNN_B ((NQ / QB) * 2)   // 1024 scan blocks
#define GEMM_B (NQ / 64)        // 512 MLP blocks = exactly 2 per CU
#define NGRP 8                  // stats atomic groups (2048 addresses)

typedef __attribute__((ext_vector_type(8))) short bf16x8;   // 8 bf16 (4 VGPRs)
typedef __attribute__((ext_vector_type(4))) float floatx4;  // MFMA accumulator
typedef unsigned short ushort_t;

__device__ __forceinline__ unsigned umin_(unsigned a, unsigned b) { return a < b ? a : b; }
__device__ __forceinline__ unsigned umax_(unsigned a, unsigned b) { return a > b ? a : b; }
#define KSWAP(a, b) { unsigned t_ = umin_(a, b); b = umax_(a, b); a = t_; }

// RNE fp32 -> bf16 pair packed in u32 (lo = a, hi = b)
__device__ __forceinline__ unsigned bf16pair(float a, float b) {
    unsigned ua = __float_as_uint(a); ua = (ua + 0x7FFFu + ((ua >> 16) & 1u)) >> 16;
    unsigned ub = __float_as_uint(b); ub = (ub + 0x7FFFu + ((ub >> 16) & 1u)) >> 16;
    return ua | (ub << 16);
}
__device__ __forceinline__ ushort_t bf16one(float a) {
    unsigned ua = __float_as_uint(a);
    return (ushort_t)((ua + 0x7FFFu + ((ua >> 16) & 1u)) >> 16);
}

// ---------------------------------------------------------------------------
// KNN scan (R11-proven) + piggy-backed weight conversion + stats/barrier zero.
// ---------------------------------------------------------------------------
__global__ __launch_bounds__(TB) void knn_kernel(const float* __restrict__ pos1,
                                                 const float* __restrict__ pos2,
                                                 unsigned* __restrict__ skeys,
                                                 const float* __restrict__ W0,
                                                 const float* __restrict__ W1,
                                                 const float* __restrict__ W2,
                                                 ushort_t* __restrict__ Wbf,
                                                 float* __restrict__ stats) {
    __shared__ __align__(16) float4 sp4[CH * 3 / 4];   // 24 KB packed xyzxyz...
    __shared__ unsigned skey[QB][NW * 4];              // 8 KB survivor keys

    if (blockIdx.x >= KNN_B) {                 // ---- prep blocks ----
        const int pb = blockIdx.x - KNN_B;     // 0..7
        const int f = pb * TB + threadIdx.x;   // float4 index within a layer
        const float* Ws[3] = {W0, W1, W2};
#pragma unroll
        for (int l = 0; l < 3; ++l) {
            const float4 v = ((const float4*)Ws[l])[f];
            unsigned* dst = (unsigned*)(Wbf + (size_t)l * CC * CC);
            dst[f * 2 + 0] = bf16pair(v.x, v.y);
            dst[f * 2 + 1] = bf16pair(v.z, v.w);
        }
        if (pb == 0)   // zero stats (3 layers x 8 groups x 256) + cnt/gen
            for (int i = threadIdx.x; i < 3 * NGRP * 256 + 8; i += TB) stats[i] = 0.f;
        return;
    }

    const int half = blockIdx.x & 1;
    const int bq   = blockIdx.x >> 1;
    const int wv = threadIdx.x >> 6;   // wave 0..7
    const int ln = threadIdx.x & 63;   // lane = query owner
    const int q  = bq * QB + ln;

    const float px = pos1[q * 3 + 0];
    const float py = pos1[q * 3 + 1];
    const float pz = pos1[q * 3 + 2];

    unsigned k0 = 0xFFFFFFFFu, k1 = 0xFFFFFFFFu, k2 = 0xFFFFFFFFu, k3 = 0xFFFFFFFFu;

    for (int c0 = 0; c0 < NCH; ++c0) {
        const int cb = half * HM + c0 * CH;
        __syncthreads();
        {   // stage 24 KB chunk, coalesced float4 copy
            const float4* g4 = (const float4*)(pos2 + (size_t)cb * 3);
#pragma unroll
            for (int i = threadIdx.x; i < CH * 3 / 4; i += TB) sp4[i] = g4[i];
        }
        __syncthreads();
        const float4* b4 = sp4 + wv * (SLC * 3 / 4);
        const int jb = cb + wv * SLC;
#pragma unroll 4
        for (int gi = 0; gi < SLC / 4; ++gi) {
            const float4 A = b4[gi * 3 + 0];
            const float4 B = b4[gi * 3 + 1];
            const float4 Cv = b4[gi * 3 + 2];
            const int j = jb + gi * 4;
            const float cx[4] = {A.x, A.w, B.z, Cv.y};
            const float cy[4] = {A.y, B.x, B.w, Cv.z};
            const float cz[4] = {A.z, B.y, Cv.x, Cv.w};
            unsigned e0, e1, e2, e3;
            {
                float dx = px - cx[0], dy = py - cy[0], dz = pz - cz[0];
                e0 = (__float_as_uint(fmaf(dx, dx, fmaf(dy, dy, dz * dz))) & KMASK) | (unsigned)(j + 0);
                dx = px - cx[1]; dy = py - cy[1]; dz = pz - cz[1];
                e1 = (__float_as_uint(fmaf(dx, dx, fmaf(dy, dy, dz * dz))) & KMASK) | (unsigned)(j + 1);
                dx = px - cx[2]; dy = py - cy[2]; dz = pz - cz[2];
                e2 = (__float_as_uint(fmaf(dx, dx, fmaf(dy, dy, dz * dz))) & KMASK) | (unsigned)(j + 2);
                dx = px - cx[3]; dy = py - cy[3]; dz = pz - cz[3];
                e3 = (__float_as_uint(fmaf(dx, dx, fmaf(dy, dy, dz * dz))) & KMASK) | (unsigned)(j + 3);
            }
            // sort e0..e3 ascending (5 comparators)
            KSWAP(e0, e1); KSWAP(e2, e3); KSWAP(e0, e2); KSWAP(e1, e3); KSWAP(e1, e2);
            // bitonic lower-half of (k asc ++ e desc)
            unsigned m0 = umin_(k0, e3), m1 = umin_(k1, e2);
            unsigned m2 = umin_(k2, e1), m3 = umin_(k3, e0);
            // sort the bitonic 4 (half-cleaner + final)
            KSWAP(m0, m2); KSWAP(m1, m3); KSWAP(m0, m1); KSWAP(m2, m3);
            k0 = m0; k1 = m1; k2 = m2; k3 = m3;
        }
    }
    skey[ln][wv * 4 + 0] = k0;
    skey[ln][wv * 4 + 1] = k1;
    skey[ln][wv * 4 + 2] = k2;
    skey[ln][wv * 4 + 3] = k3;
    __syncthreads();

#pragma unroll
    for (int t = threadIdx.x * 4; t < threadIdx.x * 4 + 4; ++t) {
        const int ql = t >> 5, slot = t & 31;
        skeys[(size_t)(bq * QB + ql) * NSURV + half * 32 + slot] = skey[ql][slot];
    }
}

// ---------------------------------------------------------------------------
// Persistent MLP kernel: 512 blocks x 256 thr. LDS 55.5 KB -> HW can place
// at most 2 blocks/CU; grid = 2 x 256 CUs => ALL blocks co-resident by
// construction (no cooperative API). Inter-layer activations stay in MFMA
// accumulators; only BN stats cross blocks via 8-group device-scope
// atomicAdd + a manual global barrier (single cnt/gen pair; thread-0 spin).
// Phases: fp64 rerank -> interp->xa -> [gemm l; bias; stats publish; gbar;
// stats reduce -> BN] x3 -> final BN+ReLU -> LDS-staged coalesced store.
// ---------------------------------------------------------------------------
struct MlpP {
    const float* feat2;
    const unsigned* skeys;
    const float* pos1;
    const float* pos2;
    const ushort_t* Wbf;
    const float* bias0; const float* bias1; const float* bias2;
    const float* g0;    const float* g1;    const float* g2;
    const float* be0;   const float* be1;   const float* be2;
    float* stats;       // 3 x NGRP x 256, zeroed by knn prep
    unsigned* bar;      // cnt, gen (zeroed by knn prep)
    float* out;
};

__device__ __forceinline__ void gbar(unsigned* cnt, unsigned* gen) {
    __syncthreads();   // also drains vmcnt: all prior stores/atomics complete
    if (threadIdx.x == 0) {
        const unsigned g = __hip_atomic_load(gen, __ATOMIC_RELAXED, __HIP_MEMORY_SCOPE_AGENT);
        const unsigned old = __hip_atomic_fetch_add(cnt, 1u, __ATOMIC_ACQ_REL, __HIP_MEMORY_SCOPE_AGENT);
        if (old == (unsigned)(GEMM_B - 1)) {
            __hip_atomic_store(cnt, 0u, __ATOMIC_RELAXED, __HIP_MEMORY_SCOPE_AGENT);
            __hip_atomic_store(gen, g + 1u, __ATOMIC_RELEASE, __HIP_MEMORY_SCOPE_AGENT);
        } else {
            while (__hip_atomic_load(gen, __ATOMIC_ACQUIRE, __HIP_MEMORY_SCOPE_AGENT) == g)
                __builtin_amdgcn_s_sleep(8);
        }
    }
    __syncthreads();
}

__global__ __launch_bounds__(256, 2) void mlp_persist(MlpP P) {
    __shared__ __align__(16) short xa[64][136];    // 17 KB: X tile bf16
    __shared__ __align__(16) short wb[128][136];   // 34 KB: W tile bf16 / fp32 out staging
    __shared__ float blk_s[CC], blk_q[CC];
    __shared__ float sc_l[CC], sh_l[CC];
    __shared__ int   lidx[QB][3];
    __shared__ float lw[QB][3];

    const int row0 = blockIdx.x * 64;
    const int lane = threadIdx.x & 63;
    const int wv = threadIdx.x >> 6;     // wave -> rows 16*wv..+15
    const int nn = lane & 15;
    const int quad = lane >> 4;

    // ===== exact fp64 re-rank of this block's 64 queries (4 thr/query) =====
    {
        double* rrd = (double*)&xa[0][0];   // [64][4][3] scratch (6144 B)
        int*    rri = (int*)&wb[0][0];      // [64][4][3] scratch (3072 B)
        const int ql = threadIdx.x >> 2;
        const int pp = threadIdx.x & 3;
        const int qg = row0 + ql;
        const double qx = (double)P.pos1[qg * 3 + 0];
        const double qy = (double)P.pos1[qg * 3 + 1];
        const double qz = (double)P.pos1[qg * 3 + 2];
        double b0 = DBL_BIG, b1 = DBL_BIG, b2 = DBL_BIG;
        int    j0 = IDX_BIG, j1 = IDX_BIG, j2 = IDX_BIG;
        const uint4* kp = (const uint4*)(P.skeys + (size_t)qg * NSURV + pp * 16);
#pragma unroll
        for (int gi = 0; gi < 4; ++gi) {
            const uint4 kk = kp[gi];
            const unsigned ks[4] = {kk.x, kk.y, kk.z, kk.w};
#pragma unroll
            for (int u = 0; u < 4; ++u) {
                const int id = (int)(ks[u] & IMASK);
                const double x = (double)P.pos2[id * 3 + 0];
                const double y = (double)P.pos2[id * 3 + 1];
                const double z = (double)P.pos2[id * 3 + 2];
                const double ax = qx - x, ay = qy - y, az = qz - z;
                const double d = ax * ax + ay * ay + az * az;
                const bool l2 = (d < b2) || (d == b2 && id < j2);
                if (l2) {
                    const bool l1 = (d < b1) || (d == b1 && id < j1);
                    const bool l0 = (d < b0) || (d == b0 && id < j0);
                    b2 = l1 ? b1 : d;              j2 = l1 ? j1 : id;
                    b1 = l1 ? (l0 ? b0 : d) : b1;  j1 = l1 ? (l0 ? j0 : id) : j1;
                    b0 = l0 ? d : b0;              j0 = l0 ? id : j0;
                }
            }
        }
        const int base = (ql * 4 + pp) * 3;
        rrd[base + 0] = b0; rri[base + 0] = j0;
        rrd[base + 1] = b1; rri[base + 1] = j1;
        rrd[base + 2] = b2; rri[base + 2] = j2;
        __syncthreads();
        if (threadIdx.x < QB) {
            const int qq = threadIdx.x;
            double c0 = DBL_BIG, c1 = DBL_BIG, c2 = DBL_BIG;
            int    i0 = IDX_BIG, i1 = IDX_BIG, i2 = IDX_BIG;
#pragma unroll
            for (int s = 0; s < 12; ++s) {
                const double d = rrd[qq * 12 + s];
                const int   id = rri[qq * 12 + s];
                const bool l2 = (d < c2) || (d == c2 && id < i2);
                if (l2) {
                    const bool l1 = (d < c1) || (d == c1 && id < i1);
                    const bool l0 = (d < c0) || (d == c0 && id < i0);
                    c2 = l1 ? c1 : d;              i2 = l1 ? i1 : id;
                    c1 = l1 ? (l0 ? c0 : d) : c1;  i1 = l1 ? (l0 ? i0 : id) : i1;
                    c0 = l0 ? d : c0;              i0 = l0 ? id : i0;
                }
            }
            const double r0 = 1.0 / (c0 + EPS_D);
            const double r1 = 1.0 / (c1 + EPS_D);
            const double r2 = 1.0 / (c2 + EPS_D);
            const double inv = 1.0 / (r0 + r1 + r2);
            lidx[qq][0] = i0; lidx[qq][1] = i1; lidx[qq][2] = i2;
            lw[qq][0] = (float)(r0 * inv);
            lw[qq][1] = (float)(r1 * inv);
            lw[qq][2] = (float)(r2 * inv);
        }
        __syncthreads();
    }

    // ===== interp -> xa (bf16), W0 -> wb =====
#pragma unroll
    for (int e = threadIdx.x; e < 64 * 32; e += 256) {
        const int r = e >> 5, c4 = e & 31;
        const int i0 = lidx[r][0], i1 = lidx[r][1], i2 = lidx[r][2];
        const float w0 = lw[r][0], w1 = lw[r][1], w2 = lw[r][2];
        const float4 f0 = *(const float4*)&P.feat2[(size_t)i0 * CC + c4 * 4];
        const float4 f1 = *(const float4*)&P.feat2[(size_t)i1 * CC + c4 * 4];
        const float4 f2 = *(const float4*)&P.feat2[(size_t)i2 * CC + c4 * 4];
        float4 v;
        v.x = w0 * f0.x + w1 * f1.x + w2 * f2.x;
        v.y = w0 * f0.y + w1 * f1.y + w2 * f2.y;
        v.z = w0 * f0.z + w1 * f1.z + w2 * f2.z;
        v.w = w0 * f0.w + w1 * f1.w + w2 * f2.w;
        unsigned* dst = (unsigned*)&xa[r][0];
        dst[c4 * 2 + 0] = bf16pair(v.x, v.y);
        dst[c4 * 2 + 1] = bf16pair(v.z, v.w);
    }
#pragma unroll
    for (int e = threadIdx.x; e < 128 * 16; e += 256) {
        const int co = e >> 4, seg = e & 15;
        *(float4*)&wb[co][seg * 8] = *(const float4*)&P.Wbf[(size_t)co * CC + seg * 8];
    }
    __syncthreads();

    const float* biasL[3] = {P.bias0, P.bias1, P.bias2};
    const float* gL[3]    = {P.g0, P.g1, P.g2};
    const float* beL[3]   = {P.be0, P.be1, P.be2};

    floatx4 acc[8];
    // ---- gemm layer 0 ----
#pragma unroll
    for (int ct = 0; ct < 8; ++ct) acc[ct] = (floatx4){0.f, 0.f, 0.f, 0.f};
    {
        const short* arow = &xa[wv * 16 + nn][0];
#pragma unroll
        for (int ks = 0; ks < 4; ++ks) {
            const bf16x8 a = *(const bf16x8*)(arow + ks * 32 + quad * 8);
#pragma unroll
            for (int ct = 0; ct < 8; ++ct) {
                const bf16x8 b = *(const bf16x8*)(&wb[ct * 16 + nn][0] + ks * 32 + quad * 8);
                acc[ct] = __builtin_amdgcn_mfma_f32_16x16x32_bf16(a, b, acc[ct], 0, 0, 0);
            }
        }
#pragma unroll
        for (int ct = 0; ct < 8; ++ct) {
            const float bv = biasL[0][ct * 16 + nn];
#pragma unroll
            for (int r = 0; r < 4; ++r) acc[ct][r] += bv;
        }
    }

    for (int l = 0; l < 3; ++l) {
        float* stL = P.stats + l * NGRP * 256;
        // ---- stats publish: column sum/ssq of acc -> 8-group atomics ----
        __syncthreads();   // acc done; xa/wb reads finished
        if (threadIdx.x < CC) { blk_s[threadIdx.x] = 0.f; blk_q[threadIdx.x] = 0.f; }
        __syncthreads();
#pragma unroll
        for (int ct = 0; ct < 8; ++ct) {
            float s = 0.f, qv = 0.f;
#pragma unroll
            for (int r = 0; r < 4; ++r) {
                s += acc[ct][r];
                qv = fmaf(acc[ct][r], acc[ct][r], qv);
            }
            s += __shfl_xor(s, 16, 64); s += __shfl_xor(s, 32, 64);
            qv += __shfl_xor(qv, 16, 64); qv += __shfl_xor(qv, 32, 64);
            if (quad == 0) {
                atomicAdd(&blk_s[ct * 16 + nn], s);
                atomicAdd(&blk_q[ct * 16 + nn], qv);
            }
        }
        __syncthreads();
        {
            const int ch = threadIdx.x;
            const float v = (ch < CC) ? blk_s[ch] : blk_q[ch - CC];
            atomicAdd(&stL[(blockIdx.x & (NGRP - 1)) * 256 + ch], v);
        }
        // ---- global barrier: all blocks' stats visible ----
        gbar(P.bar, P.bar + 1);
        // ---- reduce 8 groups -> BN scale/shift (redundant per block) ----
        if (threadIdx.x < CC) {
            const int c = threadIdx.x;
            float s = 0.f, q = 0.f;
#pragma unroll
            for (int gr = 0; gr < NGRP; ++gr) {
                s += stL[gr * 256 + c];
                q += stL[gr * 256 + CC + c];
            }
            const float m = s * (1.f / (float)NQ);
            const float v = fmaf(-m, m, q * (1.f / (float)NQ));
            const float rstd = rsqrtf(v + EPS_BN);
            const float scl = gL[l][c] * rstd;
            sc_l[c] = scl;
            sh_l[c] = fmaf(-m, scl, beL[l][c]);
        }
        __syncthreads();

        if (l < 2) {
            // ---- BN+ReLU in-register -> xa (bf16); stage W(l+1) ----
#pragma unroll
            for (int ct = 0; ct < 8; ++ct) {
                const int col = ct * 16 + nn;
                const float scl = sc_l[col], shf = sh_l[col];
#pragma unroll
                for (int r = 0; r < 4; ++r) {
                    const int row = wv * 16 + quad * 4 + r;
                    const float v = fmaxf(fmaf(acc[ct][r], scl, shf), 0.f);
                    ((ushort_t*)&xa[row][0])[col] = bf16one(v);
                }
            }
            const ushort_t* Wp = P.Wbf + (size_t)(l + 1) * CC * CC;
#pragma unroll
            for (int e = threadIdx.x; e < 128 * 16; e += 256) {
                const int co = e >> 4, seg = e & 15;
                *(float4*)&wb[co][seg * 8] = *(const float4*)&Wp[(size_t)co * CC + seg * 8];
            }
            __syncthreads();
            // ---- gemm layer l+1 ----
#pragma unroll
            for (int ct = 0; ct < 8; ++ct) acc[ct] = (floatx4){0.f, 0.f, 0.f, 0.f};
            const short* arow = &xa[wv * 16 + nn][0];
#pragma unroll
            for (int ks = 0; ks < 4; ++ks) {
                const bf16x8 a = *(const bf16x8*)(arow + ks * 32 + quad * 8);
#pragma unroll
                for (int ct = 0; ct < 8; ++ct) {
                    const bf16x8 b = *(const bf16x8*)(&wb[ct * 16 + nn][0] + ks * 32 + quad * 8);
                    acc[ct] = __builtin_amdgcn_mfma_f32_16x16x32_bf16(a, b, acc[ct], 0, 0, 0);
                }
            }
#pragma unroll
            for (int ct = 0; ct < 8; ++ct) {
                const float bv = biasL[l + 1][ct * 16 + nn];
#pragma unroll
                for (int r = 0; r < 4; ++r) acc[ct][r] += bv;
            }
        } else {
            // ---- final BN+ReLU -> wb (fp32 staging) -> coalesced store ----
            float* wf = (float*)&wb[0][0];   // [64][132] fp32, 528 B rows
#pragma unroll
            for (int ct = 0; ct < 8; ++ct) {
                const int col = ct * 16 + nn;
                const float scl = sc_l[col], shf = sh_l[col];
#pragma unroll
                for (int r = 0; r < 4; ++r) {
                    const int row = wv * 16 + quad * 4 + r;
                    wf[row * 132 + col] = fmaxf(fmaf(acc[ct][r], scl, shf), 0.f);
                }
            }
            __syncthreads();
#pragma unroll
            for (int it = 0; it < 8; ++it) {
                const int idx = it * 256 + threadIdx.x;   // float4 index
                const int row = idx >> 5, c4 = idx & 31;
                const float4 v = *(const float4*)&wf[row * 132 + c4 * 4];
                *(float4*)&P.out[(size_t)(row0 + row) * CC + c4 * 4] = v;
            }
        }
    }
}

// ---------------------------------------------------------------------------
extern "C" void kernel_launch(void* const* d_in, const int* in_sizes, int n_in,
                              void* d_out, int out_size, void* d_ws, size_t ws_size,
                              hipStream_t stream) {
    (void)in_sizes; (void)n_in; (void)out_size; (void)ws_size;

    const float* pos1  = (const float*)d_in[0];
    const float* pos2  = (const float*)d_in[1];
    const float* feat2 = (const float*)d_in[2];
    const float* Wl[3]  = {(const float*)d_in[3], (const float*)d_in[7],  (const float*)d_in[11]};
    const float* bl[3]  = {(const float*)d_in[4], (const float*)d_in[8],  (const float*)d_in[12]};
    const float* gl[3]  = {(const float*)d_in[5], (const float*)d_in[9],  (const float*)d_in[13]};
    const float* bel[3] = {(const float*)d_in[6], (const float*)d_in[10], (const float*)d_in[14]};

    // Workspace layout
    float* ws = (float*)d_ws;
    unsigned* skeys = (unsigned*)ws;                       // NQ*64 u32 (8 MB)
    float* stats = (float*)(skeys + (size_t)NQ * NSURV);   // 3*NGRP*256 + 8
    unsigned* bar = (unsigned*)(stats + 3 * NGRP * 256);   // cnt, gen (in the +8)
    ushort_t* Wbf = (ushort_t*)(stats + 3 * NGRP * 256 + 8);   // 3*16384 bf16

    // 1: KNN scan + W bf16 prep + stats/barrier zero
    knn_kernel<<<KNN_B + 8, TB, 0, stream>>>(pos1, pos2, skeys,
                                             Wl[0], Wl[1], Wl[2], Wbf, stats);
    // 2: whole MLP in one persistent kernel (512 blocks = 2/CU by LDS cap)
    MlpP P;
    P.feat2 = feat2; P.skeys = skeys; P.pos1 = pos1; P.pos2 = pos2;
    P.Wbf = Wbf;
    P.bias0 = bl[0]; P.bias1 = bl[1]; P.bias2 = bl[2];
    P.g0 = gl[0]; P.g1 = gl[1]; P.g2 = gl[2];
    P.be0 = bel[0]; P.be1 = bel[1]; P.be2 = bel[2];
    P.stats = stats; P.bar = bar; P.out = (float*)d_out;
    mlp_persist<<<GEMM_B, 256, 0, stream>>>(P);
}

// Round 13
// 208.565 us; speedup vs baseline: 1.4874x; 1.4874x over previous
//
#include <hip/hip_runtime.h>
#include <math.h>

// Problem constants (from reference)
#define NQ 32768   // query points (pos1)
#define MC 8192    // source points (pos2)
#define CC 128     // channels
#define EPS_BN 1e-5f
#define EPS_D  1e-8

#define DBL_BIG 1e300
#define IDX_BIG 0x7fffffff

// KNN config (R11-proven: 77 us)
#define QB  64          // queries per block (1 per lane)
#define TB  512         // threads per block (8 waves)
#define NW  8           // waves per block
#define CH  2048        // candidates staged per chunk
#define HM  (MC / 2)    // half of M per block = 4096
#define NCH (HM / CH)   // 2 chunks per block
#define SLC (CH / NW)   // per-chunk per-wave slice = 256
#define KMASK 0xFFFFE000u   // keep sign+exp+10 mantissa bits
#define IMASK 0x1FFFu       // 13-bit index (M=8192)
#define NSURV 64            // survivors per query (2 halves x 8 waves x 4)
#define KNN_B ((NQ / QB) * 2)   // 1024 scan blocks
#define GEMM_B (NQ / 64)        // 512
#define NGRP 64                 // stats atomic groups (8 adds/address tail)

typedef __attribute__((ext_vector_type(8))) short bf16x8;   // 8 bf16 (4 VGPRs)
typedef __attribute__((ext_vector_type(4))) float floatx4;  // MFMA accumulator
typedef unsigned short ushort_t;

__device__ __forceinline__ unsigned umin_(unsigned a, unsigned b) { return a < b ? a : b; }
__device__ __forceinline__ unsigned umax_(unsigned a, unsigned b) { return a > b ? a : b; }
#define KSWAP(a, b) { unsigned t_ = umin_(a, b); b = umax_(a, b); a = t_; }

// RNE fp32 -> bf16 pair packed in u32 (lo = a, hi = b)
__device__ __forceinline__ unsigned bf16pair(float a, float b) {
    unsigned ua = __float_as_uint(a); ua = (ua + 0x7FFFu + ((ua >> 16) & 1u)) >> 16;
    unsigned ub = __float_as_uint(b); ub = (ub + 0x7FFFu + ((ub >> 16) & 1u)) >> 16;
    return ua | (ub << 16);
}
__device__ __forceinline__ ushort_t bf16one(float a) {
    unsigned ua = __float_as_uint(a);
    return (ushort_t)((ua + 0x7FFFu + ((ua >> 16) & 1u)) >> 16);
}
// unpack u32 = (lo bf16, hi bf16) -> fp32
__device__ __forceinline__ float bflo(unsigned u) { return __uint_as_float(u << 16); }
__device__ __forceinline__ float bfhi(unsigned u) { return __uint_as_float(u & 0xFFFF0000u); }

// ---------------------------------------------------------------------------
// KNN scan (R11-proven) + piggy-backed weight conversion + stats zero.
// Blocks [0, KNN_B): 64 queries x half of M; bitonic-merge top-4 keeper.
// Blocks [KNN_B, KNN_B+8): convert W0/W1/W2 fp32 -> bf16; each prep block
// also zeroes 1/8 of the stats accumulators (3 layers x NGRP x 256).
// ---------------------------------------------------------------------------
__global__ __launch_bounds__(TB) void knn_kernel(const float* __restrict__ pos1,
                                                 const float* __restrict__ pos2,
                                                 unsigned* __restrict__ skeys,
                                                 const float* __restrict__ W0,
                                                 const float* __restrict__ W1,
                                                 const float* __restrict__ W2,
                                                 ushort_t* __restrict__ Wbf,
                                                 float* __restrict__ stats) {
    __shared__ __align__(16) float4 sp4[CH * 3 / 4];   // 24 KB packed xyzxyz...
    __shared__ unsigned skey[QB][NW * 4];              // 8 KB survivor keys

    if (blockIdx.x >= KNN_B) {                 // ---- prep blocks ----
        const int pb = blockIdx.x - KNN_B;     // 0..7
        const int f = pb * TB + threadIdx.x;   // float4 index within a layer
        const float* Ws[3] = {W0, W1, W2};
#pragma unroll
        for (int l = 0; l < 3; ++l) {
            const float4 v = ((const float4*)Ws[l])[f];
            unsigned* dst = (unsigned*)(Wbf + (size_t)l * CC * CC);
            dst[f * 2 + 0] = bf16pair(v.x, v.y);
            dst[f * 2 + 1] = bf16pair(v.z, v.w);
        }
        // zero stats: each prep block handles a 1/8 stripe
        for (int i = pb * TB + threadIdx.x; i < 3 * NGRP * 256; i += 8 * TB)
            stats[i] = 0.f;
        return;
    }

    const int half = blockIdx.x & 1;
    const int bq   = blockIdx.x >> 1;
    const int wv = threadIdx.x >> 6;   // wave 0..7
    const int ln = threadIdx.x & 63;   // lane = query owner
    const int q  = bq * QB + ln;

    const float px = pos1[q * 3 + 0];
    const float py = pos1[q * 3 + 1];
    const float pz = pos1[q * 3 + 2];

    unsigned k0 = 0xFFFFFFFFu, k1 = 0xFFFFFFFFu, k2 = 0xFFFFFFFFu, k3 = 0xFFFFFFFFu;

    for (int c0 = 0; c0 < NCH; ++c0) {
        const int cb = half * HM + c0 * CH;
        __syncthreads();
        {   // stage 24 KB chunk, coalesced float4 copy
            const float4* g4 = (const float4*)(pos2 + (size_t)cb * 3);
#pragma unroll
            for (int i = threadIdx.x; i < CH * 3 / 4; i += TB) sp4[i] = g4[i];
        }
        __syncthreads();
        const float4* b4 = sp4 + wv * (SLC * 3 / 4);
        const int jb = cb + wv * SLC;
#pragma unroll 4
        for (int gi = 0; gi < SLC / 4; ++gi) {
            const float4 A = b4[gi * 3 + 0];
            const float4 B = b4[gi * 3 + 1];
            const float4 Cv = b4[gi * 3 + 2];
            const int j = jb + gi * 4;
            const float cx[4] = {A.x, A.w, B.z, Cv.y};
            const float cy[4] = {A.y, B.x, B.w, Cv.z};
            const float cz[4] = {A.z, B.y, Cv.x, Cv.w};
            unsigned e0, e1, e2, e3;
            {
                float dx = px - cx[0], dy = py - cy[0], dz = pz - cz[0];
                e0 = (__float_as_uint(fmaf(dx, dx, fmaf(dy, dy, dz * dz))) & KMASK) | (unsigned)(j + 0);
                dx = px - cx[1]; dy = py - cy[1]; dz = pz - cz[1];
                e1 = (__float_as_uint(fmaf(dx, dx, fmaf(dy, dy, dz * dz))) & KMASK) | (unsigned)(j + 1);
                dx = px - cx[2]; dy = py - cy[2]; dz = pz - cz[2];
                e2 = (__float_as_uint(fmaf(dx, dx, fmaf(dy, dy, dz * dz))) & KMASK) | (unsigned)(j + 2);
                dx = px - cx[3]; dy = py - cy[3]; dz = pz - cz[3];
                e3 = (__float_as_uint(fmaf(dx, dx, fmaf(dy, dy, dz * dz))) & KMASK) | (unsigned)(j + 3);
            }
            // sort e0..e3 ascending (5 comparators)
            KSWAP(e0, e1); KSWAP(e2, e3); KSWAP(e0, e2); KSWAP(e1, e3); KSWAP(e1, e2);
            // bitonic lower-half of (k asc ++ e desc)
            unsigned m0 = umin_(k0, e3), m1 = umin_(k1, e2);
            unsigned m2 = umin_(k2, e1), m3 = umin_(k3, e0);
            // sort the bitonic 4 (half-cleaner + final)
            KSWAP(m0, m2); KSWAP(m1, m3); KSWAP(m0, m1); KSWAP(m2, m3);
            k0 = m0; k1 = m1; k2 = m2; k3 = m3;
        }
    }
    skey[ln][wv * 4 + 0] = k0;
    skey[ln][wv * 4 + 1] = k1;
    skey[ln][wv * 4 + 2] = k2;
    skey[ln][wv * 4 + 3] = k3;
    __syncthreads();

#pragma unroll
    for (int t = threadIdx.x * 4; t < threadIdx.x * 4 + 4; ++t) {
        const int ql = t >> 5, slot = t & 31;
        skeys[(size_t)(bq * QB + ql) * NSURV + half * 32 + slot] = skey[ql][slot];
    }
}

// ---------------------------------------------------------------------------
// bf16-MFMA fused layer GEMM: Y = Xin @ W^T + bias (fp32 accumulate).
//   MODE 0: prologue re-ranks this block's own 64 queries (fp64 exact) from
//           skeys, then Xin = interp(feat2(fp32), idx, w). Y out: bf16.
//   MODE 1: X loads hoisted to registers FIRST (hide HBM latency behind the
//           stats reduce), then statsIn[64][256] -> BN scale/shift in LDS
//           (u0/u1), then Xin = relu(Xbf16*sc+sh). Y out: bf16.
// u0/u1 double as sc/sh (staging phase) and blk_s/blk_q (epilogue) -- LDS
// 52.0 KB in MODE 1 -> 3 blocks/CU. Epilogue stats -> 64-group atomicAdd
// (8 adds/address). grid = 512, block = 256.
// ---------------------------------------------------------------------------
template <int MODE>
__global__ __launch_bounds__(256) void gemm_mfma(const void* __restrict__ Xsrc_,
                                                 const unsigned* __restrict__ skeys,
                                                 const float* __restrict__ pos1,
                                                 const float* __restrict__ pos2,
                                                 const float* __restrict__ statsIn,
                                                 const float* __restrict__ gIn,
                                                 const float* __restrict__ beIn,
                                                 const ushort_t* __restrict__ Wb,
                                                 const float* __restrict__ bias,
                                                 ushort_t* __restrict__ Y,
                                                 float* __restrict__ statsOut) {
    __shared__ __align__(16) short xa[64][136];    // 17.0 KB: X tile bf16
    __shared__ __align__(16) short wb[128][136];   // 34.0 KB: W tile bf16
    __shared__ float u0[CC], u1[CC];               // 1 KB: sc/sh then blk_s/q

    const int row0 = blockIdx.x * 64;

    // ---- X tile staging (+ fused transform) ----
    if constexpr (MODE == 0) {
        const float* feat2 = (const float*)Xsrc_;
        __shared__ int   lidx[QB][3];
        __shared__ float lw[QB][3];
        {   // exact fp64 re-rank of this block's 64 queries; 4 thr/query
            double* rrd = (double*)&xa[0][0];   // [64][4][3] = 6144 B scratch
            int*    rri = (int*)&wb[0][0];      // [64][4][3] = 3072 B scratch
            const int ql = threadIdx.x >> 2;
            const int pp = threadIdx.x & 3;
            const int qg = row0 + ql;
            const double qx = (double)pos1[qg * 3 + 0];
            const double qy = (double)pos1[qg * 3 + 1];
            const double qz = (double)pos1[qg * 3 + 2];
            double b0 = DBL_BIG, b1 = DBL_BIG, b2 = DBL_BIG;
            int    j0 = IDX_BIG, j1 = IDX_BIG, j2 = IDX_BIG;
            const uint4* kp = (const uint4*)(skeys + (size_t)qg * NSURV + pp * 16);
#pragma unroll
            for (int gi = 0; gi < 4; ++gi) {
                const uint4 kk = kp[gi];
                const unsigned ks[4] = {kk.x, kk.y, kk.z, kk.w};
#pragma unroll
                for (int u = 0; u < 4; ++u) {
                    const int id = (int)(ks[u] & IMASK);
                    const double x = (double)pos2[id * 3 + 0];
                    const double y = (double)pos2[id * 3 + 1];
                    const double z = (double)pos2[id * 3 + 2];
                    const double ax = qx - x, ay = qy - y, az = qz - z;
                    const double d = ax * ax + ay * ay + az * az;
                    const bool l2 = (d < b2) || (d == b2 && id < j2);
                    if (l2) {
                        const bool l1 = (d < b1) || (d == b1 && id < j1);
                        const bool l0 = (d < b0) || (d == b0 && id < j0);
                        b2 = l1 ? b1 : d;              j2 = l1 ? j1 : id;
                        b1 = l1 ? (l0 ? b0 : d) : b1;  j1 = l1 ? (l0 ? j0 : id) : j1;
                        b0 = l0 ? d : b0;              j0 = l0 ? id : j0;
                    }
                }
            }
            const int base = (ql * 4 + pp) * 3;
            rrd[base + 0] = b0; rri[base + 0] = j0;
            rrd[base + 1] = b1; rri[base + 1] = j1;
            rrd[base + 2] = b2; rri[base + 2] = j2;
            __syncthreads();
            if (threadIdx.x < QB) {
                const int qq = threadIdx.x;
                double c0 = DBL_BIG, c1 = DBL_BIG, c2 = DBL_BIG;
                int    i0 = IDX_BIG, i1 = IDX_BIG, i2 = IDX_BIG;
#pragma unroll
                for (int s = 0; s < 12; ++s) {
                    const double d = rrd[qq * 12 + s];
                    const int   id = rri[qq * 12 + s];
                    const bool l2 = (d < c2) || (d == c2 && id < i2);
                    if (l2) {
                        const bool l1 = (d < c1) || (d == c1 && id < i1);
                        const bool l0 = (d < c0) || (d == c0 && id < i0);
                        c2 = l1 ? c1 : d;              i2 = l1 ? i1 : id;
                        c1 = l1 ? (l0 ? c0 : d) : c1;  i1 = l1 ? (l0 ? i0 : id) : i1;
                        c0 = l0 ? d : c0;              i0 = l0 ? id : i0;
                    }
                }
                const double r0 = 1.0 / (c0 + EPS_D);
                const double r1 = 1.0 / (c1 + EPS_D);
                const double r2 = 1.0 / (c2 + EPS_D);
                const double inv = 1.0 / (r0 + r1 + r2);
                lidx[qq][0] = i0; lidx[qq][1] = i1; lidx[qq][2] = i2;
                lw[qq][0] = (float)(r0 * inv);
                lw[qq][1] = (float)(r1 * inv);
                lw[qq][2] = (float)(r2 * inv);
            }
            __syncthreads();
        }
#pragma unroll
        for (int e = threadIdx.x; e < 64 * 32; e += 256) {
            const int r = e >> 5, c4 = e & 31;
            const int i0 = lidx[r][0], i1 = lidx[r][1], i2 = lidx[r][2];
            const float w0 = lw[r][0], w1 = lw[r][1], w2 = lw[r][2];
            const float4 f0 = *(const float4*)&feat2[(size_t)i0 * CC + c4 * 4];
            const float4 f1 = *(const float4*)&feat2[(size_t)i1 * CC + c4 * 4];
            const float4 f2 = *(const float4*)&feat2[(size_t)i2 * CC + c4 * 4];
            float4 v;
            v.x = w0 * f0.x + w1 * f1.x + w2 * f2.x;
            v.y = w0 * f0.y + w1 * f1.y + w2 * f2.y;
            v.z = w0 * f0.z + w1 * f1.z + w2 * f2.z;
            v.w = w0 * f0.w + w1 * f1.w + w2 * f2.w;
            unsigned* dst = (unsigned*)&xa[r][0];
            dst[c4 * 2 + 0] = bf16pair(v.x, v.y);
            dst[c4 * 2 + 1] = bf16pair(v.z, v.w);
        }
    } else {
        const ushort_t* Xbf = (const ushort_t*)Xsrc_;
        // ---- hoist X loads: issue HBM reads before the stats reduce ----
        uint4 xreg[4];
#pragma unroll
        for (int it = 0; it < 4; ++it) {
            const int e = threadIdx.x + it * 256;   // [64 rows][16 col-groups]
            const int r = e >> 4, c8 = e & 15;
            xreg[it] = *(const uint4*)&Xbf[(size_t)(row0 + r) * CC + c8 * 8];
        }
        // ---- stats reduce: 64 groups -> BN scale/shift in LDS ----
        if (threadIdx.x < CC) {
            const int c = threadIdx.x;
            float s = 0.f, q = 0.f;
#pragma unroll 8
            for (int gr = 0; gr < NGRP; ++gr) {
                s += statsIn[gr * 256 + c];
                q += statsIn[gr * 256 + CC + c];
            }
            const float m = s * (1.f / (float)NQ);
            const float v = fmaf(-m, m, q * (1.f / (float)NQ));
            const float rstd = rsqrtf(v + EPS_BN);
            const float scl = gIn[c] * rstd;
            u0[c] = scl;
            u1[c] = fmaf(-m, scl, beIn[c]);
        }
        __syncthreads();
        // ---- transform registers -> xa (bf16) ----
#pragma unroll
        for (int it = 0; it < 4; ++it) {
            const int e = threadIdx.x + it * 256;
            const int r = e >> 4, c8 = e & 15;
            const uint4 u = xreg[it];
            const float4 s0 = *(const float4*)&u0[c8 * 8];
            const float4 s1 = *(const float4*)&u0[c8 * 8 + 4];
            const float4 h0 = *(const float4*)&u1[c8 * 8];
            const float4 h1 = *(const float4*)&u1[c8 * 8 + 4];
            const float v0 = fmaxf(fmaf(bflo(u.x), s0.x, h0.x), 0.f);
            const float v1 = fmaxf(fmaf(bfhi(u.x), s0.y, h0.y), 0.f);
            const float v2 = fmaxf(fmaf(bflo(u.y), s0.z, h0.z), 0.f);
            const float v3 = fmaxf(fmaf(bfhi(u.y), s0.w, h0.w), 0.f);
            const float v4 = fmaxf(fmaf(bflo(u.z), s1.x, h1.x), 0.f);
            const float v5 = fmaxf(fmaf(bfhi(u.z), s1.y, h1.y), 0.f);
            const float v6 = fmaxf(fmaf(bflo(u.w), s1.z, h1.z), 0.f);
            const float v7 = fmaxf(fmaf(bfhi(u.w), s1.w, h1.w), 0.f);
            uint4 o;
            o.x = bf16pair(v0, v1); o.y = bf16pair(v2, v3);
            o.z = bf16pair(v4, v5); o.w = bf16pair(v6, v7);
            *(uint4*)&xa[r][c8 * 8] = o;
        }
    }
    // ---- W tile staging: pre-converted bf16, 16B copies ----
#pragma unroll
    for (int e = threadIdx.x; e < 128 * 16; e += 256) {
        const int co = e >> 4, seg = e & 15;
        *(float4*)&wb[co][seg * 8] = *(const float4*)&Wb[(size_t)co * CC + seg * 8];
    }
    __syncthreads();

    const int lane = threadIdx.x & 63;
    const int wv = threadIdx.x >> 6;     // wave -> rows 16*wv..+15
    const int nn = lane & 15;
    const int quad = lane >> 4;

    floatx4 acc[8] = {};

    const short* arow = &xa[wv * 16 + nn][0];
#pragma unroll
    for (int ks = 0; ks < 4; ++ks) {
        const bf16x8 a = *(const bf16x8*)(arow + ks * 32 + quad * 8);
#pragma unroll
        for (int ct = 0; ct < 8; ++ct) {
            const bf16x8 b = *(const bf16x8*)(&wb[ct * 16 + nn][0] + ks * 32 + quad * 8);
            acc[ct] = __builtin_amdgcn_mfma_f32_16x16x32_bf16(a, b, acc[ct], 0, 0, 0);
        }
    }

    // ---- epilogue: bias, bf16 Y store, column stats (fp32) ----
    __syncthreads();                       // sc/sh no longer needed
    if (threadIdx.x < CC) { u0[threadIdx.x] = 0.f; u1[threadIdx.x] = 0.f; }
    __syncthreads();
#pragma unroll
    for (int ct = 0; ct < 8; ++ct) {
        const float bv = bias[ct * 16 + nn];
        float s = 0.f, qv = 0.f;
#pragma unroll
        for (int r = 0; r < 4; ++r) {
            acc[ct][r] += bv;
            s += acc[ct][r];
            qv = fmaf(acc[ct][r], acc[ct][r], qv);
        }
#pragma unroll
        for (int r = 0; r < 4; ++r)
            Y[(size_t)(row0 + wv * 16 + quad * 4 + r) * CC + ct * 16 + nn] = bf16one(acc[ct][r]);
        s += __shfl_xor(s, 16, 64); s += __shfl_xor(s, 32, 64);
        qv += __shfl_xor(qv, 16, 64); qv += __shfl_xor(qv, 32, 64);
        if (quad == 0) {
            atomicAdd(&u0[ct * 16 + nn], s);
            atomicAdd(&u1[ct * 16 + nn], qv);
        }
    }
    __syncthreads();
    // 64-group global stats: 8 serialized adds/address tail
    {
        const int ch = threadIdx.x;
        const float v = (ch < CC) ? u0[ch] : u1[ch - CC];
        atomicAdd(&statsOut[(blockIdx.x & (NGRP - 1)) * 256 + ch], v);
    }
}

// ---------------------------------------------------------------------------
// Final BN + ReLU with in-kernel stats reduce; bf16 in, fp32 out.
// grid = 512 x 256; each thread handles 4 x 8 elements.
// ---------------------------------------------------------------------------
__global__ __launch_bounds__(256) void bn_final(const ushort_t* __restrict__ Y,
                                                const float* __restrict__ statsIn,
                                                const float* __restrict__ g,
                                                const float* __restrict__ be,
                                                float* __restrict__ out) {
    __shared__ float sc_l[CC], sh_l[CC];
    if (threadIdx.x < CC) {
        const int c = threadIdx.x;
        float s = 0.f, q = 0.f;
#pragma unroll 8
        for (int gr = 0; gr < NGRP; ++gr) {
            s += statsIn[gr * 256 + c];
            q += statsIn[gr * 256 + CC + c];
        }
        const float m = s * (1.f / (float)NQ);
        const float v = fmaf(-m, m, q * (1.f / (float)NQ));
        const float rstd = rsqrtf(v + EPS_BN);
        const float scl = g[c] * rstd;
        sc_l[c] = scl;
        sh_l[c] = fmaf(-m, scl, be[c]);
    }
    __syncthreads();
    const int base = blockIdx.x * 1024 + threadIdx.x;   // 8-col group index
#pragma unroll
    for (int it = 0; it < 4; ++it) {
        const int i8 = base + it * 256;
        const int c8 = (i8 & 15) * 8;
        const uint4 u = *(const uint4*)&Y[(size_t)i8 * 8];
        const float4 s0 = *(const float4*)&sc_l[c8];
        const float4 s1 = *(const float4*)&sc_l[c8 + 4];
        const float4 h0 = *(const float4*)&sh_l[c8];
        const float4 h1 = *(const float4*)&sh_l[c8 + 4];
        float4 o0, o1;
        o0.x = fmaxf(fmaf(bflo(u.x), s0.x, h0.x), 0.f);
        o0.y = fmaxf(fmaf(bfhi(u.x), s0.y, h0.y), 0.f);
        o0.z = fmaxf(fmaf(bflo(u.y), s0.z, h0.z), 0.f);
        o0.w = fmaxf(fmaf(bfhi(u.y), s0.w, h0.w), 0.f);
        o1.x = fmaxf(fmaf(bflo(u.z), s1.x, h1.x), 0.f);
        o1.y = fmaxf(fmaf(bfhi(u.z), s1.y, h1.y), 0.f);
        o1.z = fmaxf(fmaf(bflo(u.w), s1.z, h1.z), 0.f);
        o1.w = fmaxf(fmaf(bfhi(u.w), s1.w, h1.w), 0.f);
        ((float4*)out)[i8 * 2 + 0] = o0;
        ((float4*)out)[i8 * 2 + 1] = o1;
    }
}

// ---------------------------------------------------------------------------
extern "C" void kernel_launch(void* const* d_in, const int* in_sizes, int n_in,
                              void* d_out, int out_size, void* d_ws, size_t ws_size,
                              hipStream_t stream) {
    (void)in_sizes; (void)n_in; (void)out_size; (void)ws_size;

    const float* pos1  = (const float*)d_in[0];
    const float* pos2  = (const float*)d_in[1];
    const float* feat2 = (const float*)d_in[2];
    const float* Wl[3]  = {(const float*)d_in[3], (const float*)d_in[7],  (const float*)d_in[11]};
    const float* bl[3]  = {(const float*)d_in[4], (const float*)d_in[8],  (const float*)d_in[12]};
    const float* gl[3]  = {(const float*)d_in[5], (const float*)d_in[9],  (const float*)d_in[13]};
    const float* bel[3] = {(const float*)d_in[6], (const float*)d_in[10], (const float*)d_in[14]};

    // Workspace layout
    float* ws = (float*)d_ws;
    ushort_t* B0 = (ushort_t*)ws;                   // NQ*CC bf16 (8 MB)
    ushort_t* B1 = B0 + (size_t)NQ * CC;            // NQ*CC bf16 (8 MB)
    unsigned* skeys = (unsigned*)(B1 + (size_t)NQ * CC);   // NQ*64 u32 (8 MB)
    float* stats = (float*)(skeys + (size_t)NQ * NSURV);   // 3*NGRP*256 floats
    ushort_t* Wbf = (ushort_t*)(stats + 3 * NGRP * 256);   // 3*16384 bf16

    float* st0 = stats + 0 * NGRP * 256;
    float* st1 = stats + 1 * NGRP * 256;
    float* st2 = stats + 2 * NGRP * 256;

    // 1: KNN scan + W bf16 prep + stats zero
    knn_kernel<<<KNN_B + 8, TB, 0, stream>>>(pos1, pos2, skeys,
                                             Wl[0], Wl[1], Wl[2], Wbf, stats);
    // 2: layer 0 (rerank + interp fused) -> B0 (bf16), st0
    gemm_mfma<0><<<GEMM_B, 256, 0, stream>>>(feat2, skeys, pos1, pos2,
                                             nullptr, nullptr, nullptr,
                                             Wbf + 0 * CC * CC, bl[0], B0, st0);
    // 3: layer 1 (stats-reduce + BN fused) -> B1 (bf16), st1
    gemm_mfma<1><<<GEMM_B, 256, 0, stream>>>(B0, nullptr, nullptr, nullptr,
                                             st0, gl[0], bel[0],
                                             Wbf + 1 * CC * CC, bl[1], B1, st1);
    // 4: layer 2 -> B0 (bf16), st2
    gemm_mfma<1><<<GEMM_B, 256, 0, stream>>>(B1, nullptr, nullptr, nullptr,
                                             st1, gl[1], bel[1],
                                             Wbf + 2 * CC * CC, bl[2], B0, st2);
    // 5: final BN+ReLU (stats-reduce fused) -> out (fp32)
    bn_final<<<GEMM_B, 256, 0, stream>>>(B0, st2, gl[2], bel[2], (float*)d_out);
}